// Round 1
// baseline (188.501 us; speedup 1.0000x reference)
//
#include <hip/hip_runtime.h>

// NonLocalBlock3D fused pipeline:
//   proj_nt(theta), proj_nt(phi), proj_gT(g -> V^T), flash (KV-split 8),
//   merge_y, final_proj.
// All matmuls bf16 MFMA v_mfma_f32_32x32x16_bf16; fp32 accumulate.
// Verified layouts (learn_hip m74/m101/m92/m214):
//   A-frag: lane holds A[l&31][8*(l>>5)+u] (contiguous 8 bf16)
//   B-frag: lane holds B[8*(l>>5)+u][l&31]
//   C/D:    col = l&31, row = (r&3) + 8*(r>>2) + 4*(l>>5)

typedef __bf16 bf16x8 __attribute__((ext_vector_type(8)));
typedef __bf16 bf16x4 __attribute__((ext_vector_type(4)));
typedef float f32x16 __attribute__((ext_vector_type(16)));

#define DEV __device__ __forceinline__

constexpr int NROW = 8192;   // N
constexpr int CDIM = 256;    // C
constexpr int DI   = 128;    // INTER
constexpr int KVS  = 8;      // kv splits for flash

DEV int crow(int r, int h) { return (r & 3) + 8 * (r >> 2) + 4 * h; }

DEV f32x16 mfma(bf16x8 a, bf16x8 b, f32x16 c) {
    return __builtin_amdgcn_mfma_f32_32x32x16_bf16(a, b, c, 0, 0, 0);
}

// ---------------------------------------------------------------------------
// proj_nt: out[row][n] = (bf16)( x[row][:] @ w[:, n] + bias[n] )
// x fp32 [8192][256], w fp32 [256][128], out bf16 [8192][128]
// block: 256 thr (4 waves x 32 rows) -> 128 rows/block; grid 64
// ---------------------------------------------------------------------------
__global__ __launch_bounds__(256, 2) void proj_nt(
    const float* __restrict__ x, const float* __restrict__ w,
    const float* __restrict__ bias, __bf16* __restrict__ out)
{
    __shared__ __align__(16) __bf16 Wl[CDIM * DI];  // [256 k][128 n], untransposed
    const int tid = threadIdx.x;
    const int wv = tid >> 6, lane = tid & 63, l31 = lane & 31, h = lane >> 5;

    // stage W (coalesced float4 reads, contiguous b64 LDS writes)
#pragma unroll
    for (int j = 0; j < 32; ++j) {
        int cid = j * 256 + tid;                 // [0, 8192)
        float4 v = ((const float4*)w)[cid];
        bf16x4 t;
        t[0] = (__bf16)v.x; t[1] = (__bf16)v.y; t[2] = (__bf16)v.z; t[3] = (__bf16)v.w;
        *(bf16x4*)(&Wl[cid * 4]) = t;
    }
    __syncthreads();

    const int row0 = blockIdx.x * 128 + wv * 32;
    f32x16 acc[4] = {};

#pragma unroll
    for (int kk = 0; kk < 16; ++kk) {
        // a-frag: x rows, fp32 -> bf16
        const float4* xp = (const float4*)(x + (size_t)(row0 + l31) * CDIM + kk * 16 + h * 8);
        float4 a0 = xp[0], a1 = xp[1];
        bf16x8 af;
        af[0] = (__bf16)a0.x; af[1] = (__bf16)a0.y; af[2] = (__bf16)a0.z; af[3] = (__bf16)a0.w;
        af[4] = (__bf16)a1.x; af[5] = (__bf16)a1.y; af[6] = (__bf16)a1.z; af[7] = (__bf16)a1.w;
#pragma unroll
        for (int jn = 0; jn < 4; ++jn) {
            bf16x8 bf;
#pragma unroll
            for (int u = 0; u < 8; ++u)
                bf[u] = Wl[(kk * 16 + h * 8 + u) * DI + jn * 32 + l31];
            acc[jn] = mfma(af, bf, acc[jn]);
        }
    }

#pragma unroll
    for (int jn = 0; jn < 4; ++jn) {
        int col = jn * 32 + l31;
        float bv = bias[col];
#pragma unroll
        for (int r = 0; r < 16; ++r) {
            int row = row0 + crow(r, h);
            out[(size_t)row * DI + col] = (__bf16)(acc[jn][r] + bv);
        }
    }
}

// ---------------------------------------------------------------------------
// proj_gT: outT[i][row] = (bf16)( x[row][:] @ w[:, i] + bias[i] )  (transposed!)
// Swapped operands: outT = w^T (A) . x^T (B).  outT bf16 [128][8192]
// block: 256 thr; waves own i-tiles (4x32=128 i); jn loop covers 128 x-rows.
// ---------------------------------------------------------------------------
__global__ __launch_bounds__(256, 2) void proj_gT(
    const float* __restrict__ x, const float* __restrict__ w,
    const float* __restrict__ bias, __bf16* __restrict__ outT)
{
    __shared__ __align__(16) __bf16 Wl[CDIM * DI];
    const int tid = threadIdx.x;
    const int wv = tid >> 6, lane = tid & 63, l31 = lane & 31, h = lane >> 5;

#pragma unroll
    for (int j = 0; j < 32; ++j) {
        int cid = j * 256 + tid;
        float4 v = ((const float4*)w)[cid];
        bf16x4 t;
        t[0] = (__bf16)v.x; t[1] = (__bf16)v.y; t[2] = (__bf16)v.z; t[3] = (__bf16)v.w;
        *(bf16x4*)(&Wl[cid * 4]) = t;
    }
    __syncthreads();

    const int n0 = blockIdx.x * 128;   // x-row base
    f32x16 acc[4] = {};

#pragma unroll
    for (int kk = 0; kk < 16; ++kk) {
        // a-frag: A[i][c] = w[c][i]
        bf16x8 af;
#pragma unroll
        for (int u = 0; u < 8; ++u)
            af[u] = Wl[(kk * 16 + h * 8 + u) * DI + wv * 32 + l31];
#pragma unroll
        for (int jn = 0; jn < 4; ++jn) {
            // b-frag: B[c][row] = x[row][c], contiguous in c
            const float4* xp = (const float4*)(x + (size_t)(n0 + jn * 32 + l31) * CDIM + kk * 16 + h * 8);
            float4 b0 = xp[0], b1 = xp[1];
            bf16x8 bf;
            bf[0] = (__bf16)b0.x; bf[1] = (__bf16)b0.y; bf[2] = (__bf16)b0.z; bf[3] = (__bf16)b0.w;
            bf[4] = (__bf16)b1.x; bf[5] = (__bf16)b1.y; bf[6] = (__bf16)b1.z; bf[7] = (__bf16)b1.w;
            acc[jn] = mfma(af, bf, acc[jn]);
        }
    }

#pragma unroll
    for (int jn = 0; jn < 4; ++jn) {
        int xr = n0 + jn * 32 + l31;
#pragma unroll
        for (int r = 0; r < 16; ++r) {
            int i = wv * 32 + crow(r, h);
            outT[(size_t)i * NROW + xr] = (__bf16)(acc[jn][r] + bias[i]);
        }
    }
}

// ---------------------------------------------------------------------------
// flash: online-softmax attention, swapped QK^T (S^T = K.Q^T) so softmax is
// lane-local; PV as y^T = V^T . P^T. KV-split KVS=8 -> unnormalized partials.
// grid (64 qtiles, 8 splits), block 256 (4 waves x 32 q-rows).
// LDS: Kt 16KB + Vt 16KB + Pl 16KB = 48KB, all XOR-swizzled.
// ---------------------------------------------------------------------------
__global__ __launch_bounds__(256, 2) void flash(
    const __bf16* __restrict__ q, const __bf16* __restrict__ k,
    const __bf16* __restrict__ vT, float* __restrict__ yaccT,
    float* __restrict__ mlm, float* __restrict__ mll)
{
    __shared__ __align__(16) __bf16 Kt[64 * 128];        // [kv][d], swz (kv&15)<<3
    __shared__ __align__(16) __bf16 Vt[64 * 128];        // packed [d>>1][(d&1)*64+kv], swz (row&15)<<3
    __shared__ __align__(16) __bf16 Pl[4][32 * 64];      // per-wave [q][kv], swz (q&7)<<3

    const int tid = threadIdx.x;
    const int wv = tid >> 6, lane = tid & 63, l31 = lane & 31, h = lane >> 5;
    const int qt = blockIdx.x, sp = blockIdx.y;
    const int q0 = qt * 128 + wv * 32;

    // Q frags live in registers for the whole kernel (B-operand of S^T)
    bf16x8 qf[8];
#pragma unroll
    for (int kk = 0; kk < 8; ++kk)
        qf[kk] = *(const bf16x8*)(q + (size_t)(q0 + l31) * DI + kk * 16 + h * 8);

    f32x16 yacc[4] = {};
    float m = -1e30f, l = 0.f;

    for (int it = 0; it < 16; ++it) {
        const int kvb = sp * (NROW / KVS) + it * 64;

        // stage K tile [64 kv][128 d] (coalesced b128 global -> swizzled b128 LDS)
#pragma unroll
        for (int j = 0; j < 4; ++j) {
            int cid = j * 256 + tid;                  // [0,1024)
            int r = cid >> 4, dc = (cid & 15) * 8;
            bf16x8 val = *(const bf16x8*)(k + (size_t)(kvb + r) * DI + dc);
            *(bf16x8*)(&Kt[(r * 128 + dc) ^ ((r & 15) << 3)]) = val;
        }
        // stage V^T tile [128 d][64 kv], d-pairs packed into 128-wide rows
#pragma unroll
        for (int j = 0; j < 4; ++j) {
            int cid = j * 256 + tid;
            int d = cid >> 3, kvc = (cid & 7) * 8;
            bf16x8 val = *(const bf16x8*)(vT + (size_t)d * NROW + kvb + kvc);
            int rw = d >> 1, co = (d & 1) * 64 + kvc;
            *(bf16x8*)(&Vt[(rw * 128 + co) ^ ((rw & 15) << 3)]) = val;
        }
        __syncthreads();

        // S^T = K . Q^T  (D rows = kv, cols = q -> softmax over rows = lane-local)
        f32x16 sacc[2] = {};
#pragma unroll
        for (int kk = 0; kk < 8; ++kk) {
#pragma unroll
            for (int jm = 0; jm < 2; ++jm) {
                int kv = jm * 32 + l31;
                bf16x8 kf = *(const bf16x8*)(&Kt[(kv * 128 + kk * 16 + h * 8) ^ ((kv & 15) << 3)]);
                sacc[jm] = mfma(kf, qf[kk], sacc[jm]);
            }
        }

        // online softmax for q-column l31 (values split across h-pair lanes)
        float tm = -1e30f;
#pragma unroll
        for (int jm = 0; jm < 2; ++jm)
#pragma unroll
            for (int r = 0; r < 16; ++r) tm = fmaxf(tm, sacc[jm][r]);
        tm = fmaxf(tm, __shfl_xor(tm, 32));
        float mn = fmaxf(m, tm);
        float scale = __expf(m - mn);
        float ts = 0.f;
#pragma unroll
        for (int jm = 0; jm < 2; ++jm)
#pragma unroll
            for (int r = 0; r < 16; ++r) {
                float p = __expf(sacc[jm][r] - mn);
                sacc[jm][r] = p;
                ts += p;
            }
        ts += __shfl_xor(ts, 32);
        m = mn;
        l = l * scale + ts;
#pragma unroll
        for (int jd = 0; jd < 4; ++jd) yacc[jd] *= scale;

        // write P (per-wave private): Pl[q][kv]
#pragma unroll
        for (int jm = 0; jm < 2; ++jm)
#pragma unroll
            for (int r = 0; r < 16; ++r) {
                int kv = jm * 32 + crow(r, h);
                Pl[wv][(l31 * 64 + kv) ^ ((l31 & 7) << 3)] = (__bf16)sacc[jm][r];
            }
        __syncthreads();

        // y^T += V^T . P^T
        bf16x8 pf[4];
#pragma unroll
        for (int ks = 0; ks < 4; ++ks)
            pf[ks] = *(const bf16x8*)(&Pl[wv][(l31 * 64 + ks * 16 + h * 8) ^ ((l31 & 7) << 3)]);
#pragma unroll
        for (int jd = 0; jd < 4; ++jd) {
            int d = jd * 32 + l31, rw = d >> 1;
#pragma unroll
            for (int ks = 0; ks < 4; ++ks) {
                int co = (d & 1) * 64 + ks * 16 + h * 8;
                bf16x8 vf = *(const bf16x8*)(&Vt[(rw * 128 + co) ^ ((rw & 15) << 3)]);
                yacc[jd] = mfma(vf, pf[ks], yacc[jd]);
            }
        }
        __syncthreads();
    }

    // write unnormalized partials, transposed (coalesced along q)
#pragma unroll
    for (int jd = 0; jd < 4; ++jd)
#pragma unroll
        for (int r = 0; r < 16; ++r) {
            int d = jd * 32 + crow(r, h);
            yaccT[(size_t)sp * DI * NROW + (size_t)d * NROW + qt * 128 + wv * 32 + l31] = yacc[jd][r];
        }
    if (h == 0) {
        mlm[sp * NROW + q0 + l31] = m;
        mll[sp * NROW + q0 + l31] = l;
    }
}

// ---------------------------------------------------------------------------
// merge_y: combine KVS split partials -> y bf16 [8192][128]
// lanes run along q (coalesced reads of the 32MB partial buffer)
// ---------------------------------------------------------------------------
__global__ void merge_y(const float* __restrict__ yaccT,
                        const float* __restrict__ mlm, const float* __restrict__ mll,
                        __bf16* __restrict__ y)
{
    int idx = blockIdx.x * 256 + threadIdx.x;   // [0, 128*8192)
    int d = idx >> 13, qq = idx & 8191;
    float ms[KVS];
    float m = -1e30f;
#pragma unroll
    for (int s = 0; s < KVS; ++s) {
        ms[s] = mlm[s * NROW + qq];
        m = fmaxf(m, ms[s]);
    }
    float L = 0.f, acc = 0.f;
#pragma unroll
    for (int s = 0; s < KVS; ++s) {
        float e = __expf(ms[s] - m);
        L += mll[s * NROW + qq] * e;
        acc += e * yaccT[(size_t)s * DI * NROW + (size_t)d * NROW + qq];
    }
    y[(size_t)qq * DI + d] = (__bf16)(acc / L);
}

// ---------------------------------------------------------------------------
// final_proj: out[row][c] = y[row][:] @ W[:, c] + Wb[c] + x[row][c]   (fp32 out)
// block 256 thr -> 128 rows; grid 64. W staged untransposed in LDS (64KB).
// ---------------------------------------------------------------------------
__global__ __launch_bounds__(256, 2) void final_proj(
    const __bf16* __restrict__ y, const float* __restrict__ w,
    const float* __restrict__ bias, const float* __restrict__ x,
    float* __restrict__ out)
{
    __shared__ __align__(16) __bf16 Wl[DI * CDIM];  // [128 k][256 n]
    const int tid = threadIdx.x;
    const int wv = tid >> 6, lane = tid & 63, l31 = lane & 31, h = lane >> 5;

#pragma unroll
    for (int j = 0; j < 32; ++j) {
        int cid = j * 256 + tid;                // [0, 8192) float4s
        float4 v = ((const float4*)w)[cid];
        bf16x4 t;
        t[0] = (__bf16)v.x; t[1] = (__bf16)v.y; t[2] = (__bf16)v.z; t[3] = (__bf16)v.w;
        *(bf16x4*)(&Wl[cid * 4]) = t;
    }
    __syncthreads();

    const int row0 = blockIdx.x * 128 + wv * 32;
    bf16x8 af[8];
#pragma unroll
    for (int kk = 0; kk < 8; ++kk)
        af[kk] = *(const bf16x8*)(y + (size_t)(row0 + l31) * DI + kk * 16 + h * 8);

    f32x16 acc[8] = {};
#pragma unroll
    for (int kk = 0; kk < 8; ++kk) {
#pragma unroll
        for (int jn = 0; jn < 8; ++jn) {
            bf16x8 bf;
#pragma unroll
            for (int u = 0; u < 8; ++u)
                bf[u] = Wl[(kk * 16 + h * 8 + u) * CDIM + jn * 32 + l31];
            acc[jn] = mfma(af[kk], bf, acc[jn]);
        }
    }

#pragma unroll
    for (int jn = 0; jn < 8; ++jn) {
        int col = jn * 32 + l31;
        float bv = bias[col];
#pragma unroll
        for (int r = 0; r < 16; ++r) {
            int row = row0 + crow(r, h);
            out[(size_t)row * CDIM + col] = acc[jn][r] + bv + x[(size_t)row * CDIM + col];
        }
    }
}

// ---------------------------------------------------------------------------
extern "C" void kernel_launch(void* const* d_in, const int* in_sizes, int n_in,
                              void* d_out, int out_size, void* d_ws, size_t ws_size,
                              hipStream_t stream)
{
    const float* x    = (const float*)d_in[0];
    const float* g_w  = (const float*)d_in[1];
    const float* g_b  = (const float*)d_in[2];
    const float* th_w = (const float*)d_in[3];
    const float* th_b = (const float*)d_in[4];
    const float* ph_w = (const float*)d_in[5];
    const float* ph_b = (const float*)d_in[6];
    const float* W_w  = (const float*)d_in[7];
    const float* W_b  = (const float*)d_in[8];
    float* out = (float*)d_out;

    char* ws = (char*)d_ws;
    __bf16* qws  = (__bf16*)(ws);                              // 2 MB  theta
    __bf16* kws  = (__bf16*)(ws + (2ull << 20));               // 2 MB  phi
    __bf16* vTws = (__bf16*)(ws + (4ull << 20));               // 2 MB  g^T
    __bf16* yws  = (__bf16*)(ws + (6ull << 20));               // 2 MB  attn out
    float*  mlm  = (float*)(ws + (8ull << 20));                // 256 KB
    float*  mll  = (float*)(ws + (8ull << 20) + (256ull << 10)); // 256 KB
    float*  yac  = (float*)(ws + (9ull << 20));                // 32 MB partials

    proj_nt<<<64, 256, 0, stream>>>(x, th_w, th_b, qws);
    proj_nt<<<64, 256, 0, stream>>>(x, ph_w, ph_b, kws);
    proj_gT<<<64, 256, 0, stream>>>(x, g_w, g_b, vTws);
    flash<<<dim3(64, KVS), 256, 0, stream>>>(qws, kws, vTws, yac, mlm, mll);
    merge_y<<<4096, 256, 0, stream>>>(yac, mlm, mll, yws);
    final_proj<<<64, 256, 0, stream>>>(yws, W_w, W_b, x, out);
}